// Round 1
// baseline (193.509 us; speedup 1.0000x reference)
//
#include <hip/hip_runtime.h>

#define TT 1024
#define SS 128
#define FF 8
#define CC 256
#define BH 8
#define TB 8   // time-steps per block in the balanced sum kernel

// Workspace layout:
//   [0, 32 KiB)        : seg table  int32 [BH][TT]   (seg id per (b,t), clamped to SS)
//   [32 KiB, 36 KiB)   : inv table  float [BH][SS]   (1/(d*F) or 0)

// One dispatch: zero the output (needed for atomic accumulation) and, in block 0,
// compute the cumsum/segment/inverse-count tables once instead of redundantly in
// all 1024 blocks of the sum kernel.
__global__ __launch_bounds__(256) void prep_kernel(const int* __restrict__ dsrc,
                                                   int* __restrict__ segt,
                                                   float* __restrict__ invt,
                                                   float4* __restrict__ outz) {
    int tid = threadIdx.x;
    int gid = blockIdx.x * 256 + tid;
    // BH*SS*CC floats = 65536 float4 == 256 blocks * 256 threads
    outz[gid] = make_float4(0.f, 0.f, 0.f, 0.f);
    if (blockIdx.x != 0) return;

    __shared__ int dl[BH * SS];
    __shared__ int cum[BH][SS];
    for (int i = tid; i < BH * SS; i += 256) dl[i] = dsrc[i];
    __syncthreads();
    if (tid < BH) {
        int a = 0;
        for (int s = 0; s < SS; ++s) { a += dl[tid * SS + s]; cum[tid][s] = a; }
    }
    __syncthreads();
    for (int i = tid; i < BH * SS; i += 256) {
        int d = dl[i];
        invt[i] = (d > 0) ? 1.0f / (float)(d * FF) : 0.0f;
    }
    for (int i = tid; i < BH * TT; i += 256) {
        int b = i >> 10, t = i & (TT - 1);
        // seg = #{s : cum[s] <= t}  (searchsorted right), clamped to SS by construction
        int lo = 0, hi = SS;
        while (lo < hi) { int mid = (lo + hi) >> 1; if (cum[b][mid] <= t) lo = mid + 1; else hi = mid; }
        segt[i] = lo;
    }
}

#define FLUSH(SEG)                                                                        \
    {                                                                                     \
        red[tid] = acc; __syncthreads();                                                  \
        if (tid < 64) {                                                                   \
            float4 a0 = red[tid], a1 = red[tid + 64], a2 = red[tid + 128], a3 = red[tid + 192]; \
            float inv = invt[b * SS + (SEG)];                                             \
            float* o = out + ((size_t)(b * SS + (SEG)) * CC) + tid * 4;                   \
            unsafeAtomicAdd(o + 0, (a0.x + a1.x + a2.x + a3.x) * inv);                    \
            unsafeAtomicAdd(o + 1, (a0.y + a1.y + a2.y + a3.y) * inv);                    \
            unsafeAtomicAdd(o + 2, (a0.z + a1.z + a2.z + a3.z) * inv);                    \
            unsafeAtomicAdd(o + 3, (a0.w + a1.w + a2.w + a3.w) * inv);                    \
        }                                                                                 \
        __syncthreads();                                                                  \
    }

// Perfectly balanced: every block streams a fixed 8t x 8f x 256c = 64 KiB chunk.
// Segment boundaries are uniform across the block, so partials are LDS-reduced
// and flushed with one scaled atomic set per segment touched (~2 per block).
__global__ __launch_bounds__(256) void sum_kernel(const float* __restrict__ e,
                                                  const int* __restrict__ segt,
                                                  const float* __restrict__ invt,
                                                  float* __restrict__ out) {
    int t0  = blockIdx.x * TB;
    int b   = blockIdx.y;
    int tid = threadIdx.x;

    const int* st = segt + b * TT + t0;
    int seg[TB];
    #pragma unroll
    for (int m = 0; m < TB; ++m) seg[m] = st[m];
    if (seg[0] >= SS) return;   // whole tile is past the last segment: nothing to read

    // 16 independent float4 loads per thread, issued back-to-back for MLP.
    // Element j of thread tid covers row (tid>>6) + 4*j of the 64-row chunk,
    // i.e. per time-step m the thread holds v[2m] and v[2m+1] (two f-rows).
    const float4* e4 = (const float4*)e + (size_t)(b * TT + t0) * (FF * CC / 4);
    float4 v[16];
    #pragma unroll
    for (int j = 0; j < 16; ++j) v[j] = e4[j * 256 + tid];

    __shared__ float4 red[256];
    float4 acc = make_float4(0.f, 0.f, 0.f, 0.f);
    int cur = seg[0];
    #pragma unroll
    for (int m = 0; m < TB; ++m) {
        int s = seg[m];             // uniform across the block
        if (s != cur) {             // uniform branch -> syncthreads inside is safe
            FLUSH(cur);
            acc = make_float4(0.f, 0.f, 0.f, 0.f);
            cur = s;
        }
        if (s < SS) {
            float4 va = v[2 * m], vb = v[2 * m + 1];
            acc.x += va.x + vb.x;
            acc.y += va.y + vb.y;
            acc.z += va.z + vb.z;
            acc.w += va.w + vb.w;
        }
    }
    if (cur < SS) FLUSH(cur);
}

extern "C" void kernel_launch(void* const* d_in, const int* in_sizes, int n_in,
                              void* d_out, int out_size, void* d_ws, size_t ws_size,
                              hipStream_t stream) {
    const float* e   = (const float*)d_in[0];
    const int*   d   = (const int*)d_in[1];
    float*       out = (float*)d_out;

    int*   segt = (int*)d_ws;
    float* invt = (float*)((char*)d_ws + (size_t)BH * TT * sizeof(int));

    prep_kernel<<<dim3(256), 256, 0, stream>>>(d, segt, invt, (float4*)out);
    sum_kernel<<<dim3(TT / TB, BH), 256, 0, stream>>>(e, segt, invt, out);
}

// Round 2
// 182.838 us; speedup vs baseline: 1.0584x; 1.0584x over previous
//
#include <hip/hip_runtime.h>

#define TT 1024
#define SS 128
#define FF 8
#define CC 256
#define BH 8
#define TB 8   // time-steps per block

// out must be zeroed before the fused kernel accumulates into it.
__global__ __launch_bounds__(256) void zero_kernel(float4* __restrict__ out) {
    out[blockIdx.x * 256 + threadIdx.x] = make_float4(0.f, 0.f, 0.f, 0.f);
}

__device__ __forceinline__ void flush_seg(float* __restrict__ out, int b, int s,
                                          int d0, int d1, int lane, float4 acc) {
    // d[s] via wave shuffle: lane s>>1 holds d[2(s>>1)], d[2(s>>1)+1]
    int dsel = (s & 1) ? d1 : d0;          // s is wave-uniform -> every lane selects right comp
    int ds   = __shfl(dsel, s >> 1, 64);
    float inv = 1.0f / (float)(ds * FF);   // ds >= 1 whenever a t maps to s
    float* o = out + ((size_t)(b * SS + s) * CC) + lane * 4;
    unsafeAtomicAdd(o + 0, acc.x * inv);
    unsafeAtomicAdd(o + 1, acc.y * inv);
    unsafeAtomicAdd(o + 2, acc.z * inv);
    unsafeAtomicAdd(o + 3, acc.w * inv);
}

// Balanced: block = (t-tile of 8, b). Wave q owns t = 8*tile + {2q, 2q+1}.
// Cumsum recomputed per-wave via shuffle scan (no LDS, no barriers anywhere).
// Per-segment wave-local partials flushed with scaled device atomics.
__global__ __launch_bounds__(256) void fused_kernel(const float* __restrict__ e,
                                                    const int* __restrict__ dsrc,
                                                    float* __restrict__ out) {
    int x    = blockIdx.x;
    int b    = blockIdx.y;
    int tid  = threadIdx.x;
    int lane = tid & 63;
    int q    = tid >> 6;

    // ---- wave-redundant inclusive scan of d[b, :] (128 ints, 2 per lane) ----
    int2 dd = ((const int2*)(dsrc + b * SS))[lane];
    int incl = dd.x + dd.y;
    #pragma unroll
    for (int off = 1; off < 64; off <<= 1) {
        int n = __shfl_up(incl, off, 64);
        if (lane >= off) incl += n;
    }
    int cumO = incl;          // cum[2*lane+1]
    int cumE = incl - dd.y;   // cum[2*lane]

    // segment id per owned t: seg(t) = #{s : cum[s] <= t}   (searchsorted right)
    int tA = x * TB + 2 * q;
    int tB = tA + 1;
    int segA = __popcll(__ballot(cumE <= tA)) + __popcll(__ballot(cumO <= tA));
    int segB = __popcll(__ballot(cumE <= tB)) + __popcll(__ballot(cumO <= tB));
    bool vA = segA < SS;      // t beyond cum[127] contributes nothing
    bool vB = segB < SS;

    // ---- stream: wave q covers rows [16q, 16q+16) of the 64-row (t,f) chunk ----
    const float4* e4 = (const float4*)e + (size_t)(b * TT + x * TB) * (FF * CC / 4);
    const float4* w4 = e4 + (16 * q) * 64 + lane;

    float4 sA = make_float4(0.f, 0.f, 0.f, 0.f);
    float4 sB = make_float4(0.f, 0.f, 0.f, 0.f);
    if (vA) {
        #pragma unroll
        for (int j = 0; j < 8; ++j) {
            float4 v = w4[j * 64];
            sA.x += v.x; sA.y += v.y; sA.z += v.z; sA.w += v.w;
        }
    }
    if (vB) {
        #pragma unroll
        for (int j = 8; j < 16; ++j) {
            float4 v = w4[j * 64];
            sB.x += v.x; sB.y += v.y; sB.z += v.z; sB.w += v.w;
        }
    }

    // ---- flush (wave-uniform branches, no barriers) ----
    if (vA && vB && segA == segB) {
        sA.x += sB.x; sA.y += sB.y; sA.z += sB.z; sA.w += sB.w;
        flush_seg(out, b, segA, dd.x, dd.y, lane, sA);
    } else {
        if (vA) flush_seg(out, b, segA, dd.x, dd.y, lane, sA);
        if (vB) flush_seg(out, b, segB, dd.x, dd.y, lane, sB);
    }
}

extern "C" void kernel_launch(void* const* d_in, const int* in_sizes, int n_in,
                              void* d_out, int out_size, void* d_ws, size_t ws_size,
                              hipStream_t stream) {
    const float* e   = (const float*)d_in[0];
    const int*   d   = (const int*)d_in[1];
    float*       out = (float*)d_out;

    zero_kernel<<<dim3(BH * SS * CC / 4 / 256), 256, 0, stream>>>((float4*)out);
    fused_kernel<<<dim3(TT / TB, BH), 256, 0, stream>>>(e, d, out);
}

// Round 3
// 174.879 us; speedup vs baseline: 1.1065x; 1.0455x over previous
//
#include <hip/hip_runtime.h>

#define TT 1024
#define SS 128
#define FF 8
#define CC 256
#define BH 8

// One dispatch, 8192 one-wave workgroups: block (x, b) owns segment s = x>>3 and
// channel-slice ce = x&7 (32 floats). Exact writer per output slice -> no atomics,
// no zero pass. Small blocks give per-CU averaging over ~32 iid segment pieces plus
// hardware queue-drain balancing (only ~16 wg resident per CU, rest refill as CUs free).
__global__ __launch_bounds__(64) void fused_kernel(const float* __restrict__ e,
                                                   const int* __restrict__ dsrc,
                                                   float* __restrict__ out) {
    int x    = blockIdx.x;
    int b    = blockIdx.y;
    int lane = threadIdx.x;
    int s    = x >> 3;
    int ce   = x & 7;

    // ---- wave-redundant inclusive scan of d[b, :] (128 ints, 2 per lane) ----
    int2 dd = ((const int2*)(dsrc + b * SS))[lane];
    int incl = dd.x + dd.y;
    #pragma unroll
    for (int off = 1; off < 64; off <<= 1) {
        int n = __shfl_up(incl, off, 64);
        if (lane >= off) incl += n;
    }
    // cum[2l] = incl(l) - dd.y(l); cum[2l+1] = incl(l)
    int l  = s >> 1;
    int iS = __shfl(incl, l, 64);
    int xS = __shfl(dd.x, l, 64);
    int yS = __shfl(dd.y, l, 64);
    int end   = (s & 1) ? iS : (iS - yS);
    int dS    = (s & 1) ? yS : xS;
    int start = end - dS;
    if (start > TT) start = TT;
    if (end   > TT) end   = TT;
    int K = (end - start) * FF;       // rows of 256 floats; our slice = 8 float4 of each

    // lane covers float4 #fi of row k (k = r8 mod 8): 8 lanes per 128B row-chunk, 8 rows/iter
    int r8 = lane >> 3;
    int fi = lane & 7;
    const float4* base = (const float4*)e
        + (size_t)(b * TT + start) * (FF * CC / 4)
        + ce * 8 + fi;

    float4 acc = make_float4(0.f, 0.f, 0.f, 0.f);
    int k = r8;
    for (; k + 24 < K; k += 32) {     // 4 independent loads in flight
        float4 v0 = base[(size_t)(k     ) * 64];
        float4 v1 = base[(size_t)(k +  8) * 64];
        float4 v2 = base[(size_t)(k + 16) * 64];
        float4 v3 = base[(size_t)(k + 24) * 64];
        acc.x += v0.x + v1.x + v2.x + v3.x;
        acc.y += v0.y + v1.y + v2.y + v3.y;
        acc.z += v0.z + v1.z + v2.z + v3.z;
        acc.w += v0.w + v1.w + v2.w + v3.w;
    }
    for (; k < K; k += 8) {
        float4 v = base[(size_t)k * 64];
        acc.x += v.x; acc.y += v.y; acc.z += v.z; acc.w += v.w;
    }

    // reduce across r8 groups (lanes sharing lane&7): xor over bits 3,4,5
    #pragma unroll
    for (int m = 8; m < 64; m <<= 1) {
        acc.x += __shfl_xor(acc.x, m, 64);
        acc.y += __shfl_xor(acc.y, m, 64);
        acc.z += __shfl_xor(acc.z, m, 64);
        acc.w += __shfl_xor(acc.w, m, 64);
    }

    if (lane < 8) {
        float inv = (dS > 0) ? 1.0f / (float)(dS * FF) : 0.0f;
        float4 r = make_float4(acc.x * inv, acc.y * inv, acc.z * inv, acc.w * inv);
        ((float4*)out)[(size_t)(b * SS + s) * 64 + ce * 8 + lane] = r;
    }
}

extern "C" void kernel_launch(void* const* d_in, const int* in_sizes, int n_in,
                              void* d_out, int out_size, void* d_ws, size_t ws_size,
                              hipStream_t stream) {
    const float* e   = (const float*)d_in[0];
    const int*   d   = (const int*)d_in[1];
    float*       out = (float*)d_out;

    fused_kernel<<<dim3(SS * 8, BH), 64, 0, stream>>>(e, d, out);
}